// Round 17
// baseline (436.041 us; speedup 1.0000x reference)
//
#include <hip/hip_runtime.h>

#define NEG_SLOPE 0.2f
#define LN_EPS 1e-5f
#define LOG2E 1.44269504088896f

typedef __attribute__((ext_vector_type(2))) _Float16 h16x2;
typedef __attribute__((ext_vector_type(8))) _Float16 h16x8;
typedef __attribute__((ext_vector_type(4))) float f32x4;

__device__ __forceinline__ h16x2 u2h(unsigned u) { return __builtin_bit_cast(h16x2, u); }
// f32 pair -> packed fp16 (RTZ) as raw u32 / as h16x2
__device__ __forceinline__ unsigned pk(float a, float b) {
    return __builtin_bit_cast(unsigned, __builtin_amdgcn_cvt_pkrtz(a, b));
}
__device__ __forceinline__ h16x2 pkh(float a, float b) {
    return __builtin_bit_cast(h16x2, __builtin_amdgcn_cvt_pkrtz(a, b));
}

// DPP sum over each 16-lane row: xor1(quad_perm 0xB1), xor2(0x4E),
// xor7(row_half_mirror 0x141), xor15(row_mirror 0x140) covers all 16 lanes.
#define DPP_ADD(v, ctrl) \
    v += __int_as_float(__builtin_amdgcn_update_dpp(0, __float_as_int(v), ctrl, 0xF, 0xF, true))
__device__ __forceinline__ float dpp_sum16(float v) {
    DPP_ADD(v, 0xB1);
    DPP_ADD(v, 0x4E);
    DPP_ADD(v, 0x141);
    DPP_ADD(v, 0x140);
    return v;
}
// sum over each 8-lane group: xor1, xor2, then half-row mirror (groups equal)
__device__ __forceinline__ float dpp_sum8(float v) {
    DPP_ADD(v, 0xB1);
    DPP_ADD(v, 0x4E);
    DPP_ADD(v, 0x141);
    return v;
}

// ---------- one-shot prep: 8 weight matrices + 2 embedding tables fp32->fp16,
// plus zeroing the CSR counter arrays (replaces a memset dispatch).
// blocks: [0,128) weights | [128,128+nb0) emb0 | [..+nb1) emb1 | rest: zero cnt
struct WSrc8 { const float* s[8]; };
__global__ __launch_bounds__(256) void prep_kernel(
    WSrc8 W, unsigned short* wdst,
    const float* e0, unsigned short* d0, int n0,
    const float* e1, unsigned short* d1, int nb0, int nb1,
    int* zeros, int nzero)
{
    if (blockIdx.x >= (unsigned)(128 + nb0 + nb1)) {      // zero branch: int4 stores
        int zi = (blockIdx.x - 128 - nb0 - nb1) * 1024 + threadIdx.x * 4;
        if (zi < nzero) *(int4*)(zeros + zi) = make_int4(0, 0, 0, 0);
        return;
    }
    const float* src; unsigned short* dst; int idx; int lim;
    if (blockIdx.x < 128) {
        int gidx = blockIdx.x * 256 + threadIdx.x;
        int mid = gidx >> 12;                    // 4096 threads per matrix
        src = W.s[mid]; dst = wdst + mid * 16384;
        idx = (gidx & 4095); lim = 4096;
    } else if (blockIdx.x < (unsigned)(128 + nb0)) {
        src = e0; dst = d0; idx = (blockIdx.x - 128) * 256 + threadIdx.x; lim = n0 * 16;
    } else {
        src = e1; dst = d1; idx = (blockIdx.x - 128 - nb0) * 256 + threadIdx.x; lim = 1 << 30;
    }
    if (idx >= lim) return;
    float4 v = *(const float4*)(src + idx * 4);
    uint2 o;
    o.x = pk(v.x, v.y);
    o.y = pk(v.z, v.w);
    *(uint2*)(dst + idx * 4) = o;
}

struct LinJob {
    const unsigned short* x; const int* ids; const unsigned short* Wh;
    const float* bias; unsigned short* out; int n;
};
struct LinJob4 { LinJob j[4]; };

// ---------- gather + linear via f16 MFMA, 4 jobs per launch, 2-way tile ILP:
// D[ncol][node] = W·x^T (two independent 16-row tiles in flight per iter)
__global__ __launch_bounds__(256) void lin4_kernel(LinJob4 P, int bpj)
{
    int jid = blockIdx.x / bpj;
    LinJob job = P.j[jid];
    int blk = blockIdx.x - jid * bpj;
    const int* __restrict__ ids = job.ids;
    const unsigned short* __restrict__ x = job.x;
    int n = job.n;

    int wv = threadIdx.x >> 6;
    int lane = threadIdx.x & 63;
    int m = lane & 15, q = lane >> 4;
    h16x8 wfrag[4][2];   // A-operand: lane holds i = wv*64+t*16+m, k = q*8 + h*32
#pragma unroll
    for (int t = 0; t < 4; ++t) {
        const unsigned short* wr = job.Wh + (wv * 64 + t * 16 + m) * 64 + q * 8;
#pragma unroll
        for (int h = 0; h < 2; ++h)
            wfrag[t][h] = *(const h16x8*)(wr + h * 32);
    }
    float4 biasv[4];
#pragma unroll
    for (int t = 0; t < 4; ++t)
        biasv[t] = *(const float4*)(job.bias + wv * 64 + t * 16 + q * 4);

    int ntiles = (n + 15) >> 4;
    for (int t0 = blk * 2; t0 < ntiles; t0 += bpj * 2) {
        int t1 = (t0 + 1 < ntiles) ? t0 + 1 : t0;
        int rowA = t0 * 16 + m, rowB = t1 * 16 + m;
        int rA = rowA < n ? rowA : n - 1;
        int rB = rowB < n ? rowB : n - 1;
        int sA = ids ? ids[rA] : rA;
        int sB = ids ? ids[rB] : rB;
        const unsigned short* xrA = x + (size_t)sA * 64 + q * 8;
        const unsigned short* xrB = x + (size_t)sB * 64 + q * 8;
        h16x8 xfA[2], xfB[2];                 // 4 independent b128 gathers
        xfA[0] = *(const h16x8*)(xrA);
        xfA[1] = *(const h16x8*)(xrA + 32);
        xfB[0] = *(const h16x8*)(xrB);
        xfB[1] = *(const h16x8*)(xrB + 32);
        bool vA = rowA < n, vB = (rowB < n) && (t1 != t0);
        unsigned short* oA = job.out + (size_t)rowA * 256 + wv * 64 + q * 4;
        unsigned short* oB = job.out + (size_t)rowB * 256 + wv * 64 + q * 4;
#pragma unroll
        for (int t = 0; t < 4; ++t) {
            f32x4 accA = {0.f, 0.f, 0.f, 0.f};
            accA = __builtin_amdgcn_mfma_f32_16x16x32_f16(wfrag[t][0], xfA[0], accA, 0, 0, 0);
            accA = __builtin_amdgcn_mfma_f32_16x16x32_f16(wfrag[t][1], xfA[1], accA, 0, 0, 0);
            f32x4 accB = {0.f, 0.f, 0.f, 0.f};
            accB = __builtin_amdgcn_mfma_f32_16x16x32_f16(wfrag[t][0], xfB[0], accB, 0, 0, 0);
            accB = __builtin_amdgcn_mfma_f32_16x16x32_f16(wfrag[t][1], xfB[1], accB, 0, 0, 0);
            if (vA) {
                uint2 o;
                o.x = pk(accA[0] + biasv[t].x, accA[1] + biasv[t].y);
                o.y = pk(accA[2] + biasv[t].z, accA[3] + biasv[t].w);
                *(uint2*)(oA + t * 16) = o;
            }
            if (vB) {
                uint2 o;
                o.x = pk(accB[0] + biasv[t].x, accB[1] + biasv[t].y);
                o.y = pk(accB[2] + biasv[t].z, accB[3] + biasv[t].w);
                *(uint2*)(oB + t * 16) = o;
            }
        }
    }
}

// ---------- CSR: histogram, both edge types in one launch
__global__ __launch_bounds__(256) void hist2_kernel(
    const int* __restrict__ ed0, int E0, int* __restrict__ cnt0,
    const int* __restrict__ ed1, int E1, int* __restrict__ cnt1)
{
    int i = blockIdx.x * 256 + threadIdx.x;
    if (i < E0) atomicAdd(&cnt0[ed0[i]], 1);
    else { int k = i - E0; if (k < E1) atomicAdd(&cnt1[ed1[k]], 1); }
}

// ---------- CSR: per-1024-chunk sums, both jobs
__global__ __launch_bounds__(256) void chunk_sum2_kernel(
    const int* __restrict__ cnt0, int* __restrict__ csum0, int n0, int nc0,
    const int* __restrict__ cnt1, int* __restrict__ csum1, int n1)
{
    const int* cnt; int* csum; int n; int blk;
    if (blockIdx.x < (unsigned)nc0) { cnt = cnt0; csum = csum0; n = n0; blk = blockIdx.x; }
    else { cnt = cnt1; csum = csum1; n = n1; blk = blockIdx.x - nc0; }
    __shared__ int wsm[4];
    int tid = threadIdx.x;
    int base = blk * 1024 + tid * 4;
    int s = 0;
#pragma unroll
    for (int k = 0; k < 4; ++k) { int i = base + k; if (i < n) s += cnt[i]; }
#pragma unroll
    for (int ofs = 32; ofs > 0; ofs >>= 1) s += __shfl_xor(s, ofs, 64);
    if ((tid & 63) == 0) wsm[tid >> 6] = s;
    __syncthreads();
    if (tid == 0) csum[blk] = wsm[0] + wsm[1] + wsm[2] + wsm[3];
}

// ---------- CSR: exclusive scan of chunk sums; wave0 -> job0, wave1 -> job1
__global__ __launch_bounds__(128) void chunk_scan2_kernel(
    int* __restrict__ c0, int n0, int* __restrict__ c1, int n1)
{
    int w = threadIdx.x >> 6, lane = threadIdx.x & 63;
    int* c = w ? c1 : c0;
    int n = w ? n1 : n0;
    int v = (lane < n) ? c[lane] : 0;
    int incl = v;
#pragma unroll
    for (int ofs = 1; ofs < 64; ofs <<= 1) {
        int t = __shfl_up(incl, ofs, 64);
        if (lane >= ofs) incl += t;
    }
    if (lane < n) c[lane] = incl - v;   // exclusive
}

// ---------- CSR: block-local scan + chunk offset, both jobs
__global__ __launch_bounds__(1024) void scan_apply2_kernel(
    const int* __restrict__ cnt0, const int* __restrict__ co0, int* __restrict__ offs0, int n0, int nc0,
    const int* __restrict__ cnt1, const int* __restrict__ co1, int* __restrict__ offs1, int n1)
{
    const int* cnt; const int* co; int* offs; int n; int blk;
    if (blockIdx.x < (unsigned)nc0) { cnt = cnt0; co = co0; offs = offs0; n = n0; blk = blockIdx.x; }
    else { cnt = cnt1; co = co1; offs = offs1; n = n1; blk = blockIdx.x - nc0; }
    __shared__ int wsum[16];
    int tid = threadIdx.x, lane = tid & 63, w = tid >> 6;
    int i = blk * 1024 + tid;
    int v = (i < n) ? cnt[i] : 0;
    int incl = v;
#pragma unroll
    for (int ofs = 1; ofs < 64; ofs <<= 1) {
        int t = __shfl_up(incl, ofs, 64);
        if (lane >= ofs) incl += t;
    }
    if (lane == 63) wsum[w] = incl;
    __syncthreads();
    if (w == 0) {
        int x = (lane < 16) ? wsum[lane] : 0;
#pragma unroll
        for (int ofs = 1; ofs < 16; ofs <<= 1) {
            int t = __shfl_up(x, ofs, 64);
            if (lane >= ofs) x += t;
        }
        if (lane < 16) wsum[lane] = x;
    }
    __syncthreads();
    int woff = (w == 0) ? 0 : wsum[w - 1];
    if (i < n) offs[i + 1] = co[blk] + woff + incl;
    if (i == 0) offs[0] = 0;
}

// ---------- CSR: scatter into sorted order, both jobs
__global__ __launch_bounds__(256) void fill2_kernel(
    const int* __restrict__ es0, const int* __restrict__ ed0,
    const int* __restrict__ offs0, int* __restrict__ cur0, int* __restrict__ srt0, int E0,
    const int* __restrict__ es1, const int* __restrict__ ed1,
    const int* __restrict__ offs1, int* __restrict__ cur1, int* __restrict__ srt1, int E1)
{
    int i = blockIdx.x * 256 + threadIdx.x;
    if (i < E0) {
        int d = ed0[i];
        int pos = offs0[d] + atomicAdd(&cur0[d], 1);
        srt0[pos] = es0[i];
    } else {
        int k = i - E0;
        if (k < E1) {
            int d = ed1[k];
            int pos = offs1[d] + atomicAdd(&cur1[d], 1);
            srt1[pos] = es1[k];
        }
    }
}

struct GatJob {
    const unsigned short* A; const unsigned short* B;
    const int* offs; const int* srt;
    const float* att; const float* bias;
    const float* lnw; const float* lnb;
    unsigned short* out; int n_dst;
};

// ---------- fused GATv2 conv, 2 jobs per launch; fp16 tables + packed-f16 math.
// 4-way edge unroll with 4 independent states. Scalarized edge walk via
// readfirstlane; exp2 softmax with -6 shift folded. lane = h*16+g; wave per dst.
__global__ __launch_bounds__(256) void gat2_kernel(GatJob j0, GatJob j1, int blocks0)
{
    GatJob job = (blockIdx.x < (unsigned)blocks0) ? j0 : j1;
    int blk = (blockIdx.x < (unsigned)blocks0) ? blockIdx.x : blockIdx.x - blocks0;
    int d = blk * 4 + (threadIdx.x >> 6);
    int lane = threadIdx.x & 63;
    if (d >= job.n_dst) return;
    int g = lane & 15;
    const uint2* __restrict__ A2 = (const uint2*)job.A;   // 64 uint2 per node row
    float4 att4 = ((const float4*)job.att)[lane];
    h16x2 att01 = pkh(att4.x * LOG2E, att4.y * LOG2E);
    h16x2 att23 = pkh(att4.z * LOG2E, att4.w * LOG2E);
    uint2 bw = ((const uint2*)(job.B + (size_t)d * 256))[lane];
    h16x2 b01 = u2h(bw.x), b23 = u2h(bw.y);
    const h16x2 zh = {(_Float16)0.f, (_Float16)0.f};
    const h16x2 ns = {(_Float16)NEG_SLOPE, (_Float16)NEG_SLOPE};

    float den1 = 0.f, den2 = 0.f, den3 = 0.f, den4 = 0.f;
    h16x2 p01 = zh, p23 = zh, q01 = zh, q23 = zh;
    h16x2 r01 = zh, r23 = zh, s01 = zh, s23 = zh;   // four f16 accumulator states
    const int* __restrict__ srt = job.srt;
    int j0i = __builtin_amdgcn_readfirstlane(job.offs[d]);
    int j1i = __builtin_amdgcn_readfirstlane(job.offs[d + 1]);
    int j = j0i;

#define EDGE_CHAIN(WB, DEN, A01, A23) { \
        h16x2 a01 = u2h(WB.x), a23 = u2h(WB.y); \
        h16x2 t01 = a01 + b01, t23 = a23 + b23; \
        h16x2 l01 = __builtin_elementwise_max(t01 * ns, t01); \
        h16x2 l23 = __builtin_elementwise_max(t23 * ns, t23); \
        float p = __builtin_amdgcn_fdot2(l23, att23, \
                    __builtin_amdgcn_fdot2(l01, att01, -0.375f, false), false); \
        p = dpp_sum16(p);                            /* logit*log2e - 6 */ \
        float pe = __builtin_amdgcn_exp2f(p); \
        DEN += pe; \
        h16x2 peh = pkh(pe, pe); \
        A01 = a01 * peh + A01; \
        A23 = a23 * peh + A23; }

    for (; j + 3 < j1i; j += 4) {
        int s0 = __builtin_amdgcn_readfirstlane(srt[j]);
        int s1 = __builtin_amdgcn_readfirstlane(srt[j + 1]);
        int s2 = __builtin_amdgcn_readfirstlane(srt[j + 2]);
        int s3 = __builtin_amdgcn_readfirstlane(srt[j + 3]);
        uint2 w0 = A2[(size_t)s0 * 64 + lane];   // 4 gathers in flight
        uint2 w1 = A2[(size_t)s1 * 64 + lane];
        uint2 w2 = A2[(size_t)s2 * 64 + lane];
        uint2 w3 = A2[(size_t)s3 * 64 + lane];
        EDGE_CHAIN(w0, den1, p01, p23)
        EDGE_CHAIN(w1, den2, q01, q23)
        EDGE_CHAIN(w2, den3, r01, r23)
        EDGE_CHAIN(w3, den4, s01, s23)
    }
    for (; j < j1i; ++j) {
        int s0 = __builtin_amdgcn_readfirstlane(srt[j]);
        uint2 w0 = A2[(size_t)s0 * 64 + lane];
        EDGE_CHAIN(w0, den1, p01, p23)
    }
#undef EDGE_CHAIN

    float den = (den1 + den2) + (den3 + den4);
    h16x2 A01 = (p01 + q01) + (r01 + s01);
    h16x2 A23 = (p23 + q23) + (r23 + s23);
    float inv = 1.f / (den + 1e-16f);          // empty segment -> 0
    float4 acc;
    acc.x = (float)A01.x * inv;
    acc.y = (float)A01.y * inv;
    acc.z = (float)A23.x * inv;
    acc.w = (float)A23.y * inv;
    acc.x += __shfl_xor(acc.x, 16, 64);
    acc.y += __shfl_xor(acc.y, 16, 64);
    acc.z += __shfl_xor(acc.z, 16, 64);
    acc.w += __shfl_xor(acc.w, 16, 64);
    acc.x += __shfl_xor(acc.x, 32, 64);
    acc.y += __shfl_xor(acc.y, 32, 64);
    acc.z += __shfl_xor(acc.z, 32, 64);
    acc.w += __shfl_xor(acc.w, 32, 64);        // sum over heads
    float4 b4 = ((const float4*)job.bias)[g];
    float4 v;
    v.x = acc.x * 0.25f + b4.x;
    v.y = acc.y * 0.25f + b4.y;
    v.z = acc.z * 0.25f + b4.z;
    v.w = acc.w * 0.25f + b4.w;
    if (job.lnw) {                             // fused relu + LayerNorm (layer 1)
        v.x = v.x > 0.f ? v.x : 0.f;
        v.y = v.y > 0.f ? v.y : 0.f;
        v.z = v.z > 0.f ? v.z : 0.f;
        v.w = v.w > 0.f ? v.w : 0.f;
        float s  = dpp_sum16(v.x + v.y + v.z + v.w);
        float ss = dpp_sum16(v.x*v.x + v.y*v.y + v.z*v.z + v.w*v.w);
        float mu = s * (1.f / 64.f);
        float var = ss * (1.f / 64.f) - mu * mu;
        float rs = rsqrtf(var + LN_EPS);
        float4 w4 = ((const float4*)job.lnw)[g];
        float4 l4 = ((const float4*)job.lnb)[g];
        v.x = (v.x - mu) * rs * w4.x + l4.x;
        v.y = (v.y - mu) * rs * w4.y + l4.y;
        v.z = (v.z - mu) * rs * w4.z + l4.z;
        v.w = (v.w - mu) * rs * w4.w + l4.w;
    }
    if (lane < 16) {
        uint2 o;
        o.x = pk(v.x, v.y);
        o.y = pk(v.z, v.w);
        *(uint2*)(job.out + (size_t)d * 64 + g * 4) = o;
    }
}

// ---------- classifier: 8 lanes per edge, uint4 fp16 loads, fdot2 + DPP sum8
__global__ __launch_bounds__(256) void dot_kernel(
    const unsigned short* __restrict__ os, const unsigned short* __restrict__ ot,
    const int* __restrict__ ea, const int* __restrict__ eb,
    float* __restrict__ out, int n)
{
    int e = (int)((blockIdx.x * 256u + threadIdx.x) >> 3);
    int l = threadIdx.x & 7;
    if (e >= n) return;
    uint4 aw = ((const uint4*)(os + (size_t)ea[e] * 64))[l];
    uint4 bw = ((const uint4*)(ot + (size_t)eb[e] * 64))[l];
    float v = __builtin_amdgcn_fdot2(u2h(aw.x), u2h(bw.x), 0.f, false);
    v = __builtin_amdgcn_fdot2(u2h(aw.y), u2h(bw.y), v, false);
    v = __builtin_amdgcn_fdot2(u2h(aw.z), u2h(bw.z), v, false);
    v = __builtin_amdgcn_fdot2(u2h(aw.w), u2h(bw.w), v, false);
    v = dpp_sum8(v);
    if (l == 0) out[e] = v;
}

extern "C" void kernel_launch(void* const* d_in, const int* in_sizes, int n_in,
                              void* d_out, int out_size, void* d_ws, size_t ws_size,
                              hipStream_t stream)
{
    const float* src_emb = (const float*)d_in[0];
    const float* tgt_emb = (const float*)d_in[1];
    const float* P[4][6];
    for (int ci = 0; ci < 4; ++ci)
        for (int k = 0; k < 6; ++k)
            P[ci][k] = (const float*)d_in[2 + ci * 6 + k];
    const float* ln_s_w = (const float*)d_in[26];
    const float* ln_s_b = (const float*)d_in[27];
    const float* ln_t_w = (const float*)d_in[28];
    const float* ln_t_b = (const float*)d_in[29];
    const int* nid_s = (const int*)d_in[30];
    const int* nid_t = (const int*)d_in[31];
    const int* ei_st = (const int*)d_in[32];
    const int* ei_ts = (const int*)d_in[33];
    const int* eli   = (const int*)d_in[34];

    int n_src = in_sizes[30];
    int n_tgt = in_sizes[31];
    int E_st = in_sizes[32] / 2;
    int E_ts = in_sizes[33] / 2;
    int EL   = in_sizes[34] / 2;
    int nmax = n_src > n_tgt ? n_src : n_tgt;

    float* ws = (float*)d_ws;
    size_t off = 0;
    auto alloc = [&](size_t count) {     // count in floats
        float* p = ws + off;
        off += (count + 63) & ~(size_t)63;
        return p;
    };
    // 4 concurrent fp16 tables [n][256]
    unsigned short* A_st = (unsigned short*)alloc((size_t)nmax * 128);
    unsigned short* B_st = (unsigned short*)alloc((size_t)nmax * 128);
    unsigned short* A_ts = (unsigned short*)alloc((size_t)nmax * 128);
    unsigned short* B_ts = (unsigned short*)alloc((size_t)nmax * 128);
    unsigned short* Whf  = (unsigned short*)alloc(65536);   // 8 x [256x64] fp16
    // fp16 embedding copies [n][64]
    unsigned short* e_s = (unsigned short*)alloc((size_t)n_src * 32);
    unsigned short* e_t = (unsigned short*)alloc((size_t)n_tgt * 32);
    int*   offs_st = (int*)alloc((size_t)n_tgt + 1);
    int*   srt_st  = (int*)alloc((size_t)E_st);
    int*   offs_ts = (int*)alloc((size_t)n_src + 1);
    int*   srt_ts  = (int*)alloc((size_t)E_ts);
    int*   zeros   = (int*)alloc((size_t)4 * nmax + 4);   // cnt0,cnt1,cur0,cur1
    int*   csum0   = (int*)alloc(64);
    int*   csum1   = (int*)alloc(64);
    // fp16 node feature tables [n][64]
    unsigned short* h_s = (unsigned short*)alloc((size_t)n_src * 32);
    unsigned short* h_t = (unsigned short*)alloc((size_t)n_tgt * 32);
    unsigned short* o_s = (unsigned short*)alloc((size_t)n_src * 32);
    unsigned short* o_t = (unsigned short*)alloc((size_t)n_tgt * 32);
    if (off * sizeof(float) > ws_size) return;

    int* cnt0 = zeros;
    int* cnt1 = zeros + nmax;
    int* cur0 = zeros + 2 * (size_t)nmax;
    int* cur1 = zeros + 3 * (size_t)nmax;

    // ---- prep: weights + fp16 embeddings + zero CSR counters (1 launch)
    WSrc8 WS;
    for (int ci = 0; ci < 4; ++ci) { WS.s[ci*2] = P[ci][0]; WS.s[ci*2+1] = P[ci][2]; }
    int nb0 = (n_src * 16 + 255) / 256;    // float4s per table / 256
    int nb1 = (n_tgt * 16 + 255) / 256;
    int nzero = 4 * nmax;
    int nbz = (nzero + 1023) / 1024;
    prep_kernel<<<128 + nb0 + nb1 + nbz, 256, 0, stream>>>(
        WS, Whf, src_emb, e_s, n_src, tgt_emb, e_t, nb0, nb1, zeros, nzero);

    // ---- CSR build for both edge types (job0: st->dst=tgt, job1: ts->dst=src)
    int nc0 = (n_tgt + 1023) / 1024, nc1 = (n_src + 1023) / 1024;   // <= 64 each
    hist2_kernel<<<(E_st + E_ts + 255) / 256, 256, 0, stream>>>(
        ei_st + E_st, E_st, cnt0, ei_ts + E_ts, E_ts, cnt1);
    chunk_sum2_kernel<<<nc0 + nc1, 256, 0, stream>>>(cnt0, csum0, n_tgt, nc0, cnt1, csum1, n_src);
    chunk_scan2_kernel<<<1, 128, 0, stream>>>(csum0, nc0, csum1, nc1);
    scan_apply2_kernel<<<nc0 + nc1, 1024, 0, stream>>>(
        cnt0, csum0, offs_st, n_tgt, nc0, cnt1, csum1, offs_ts, n_src);
    fill2_kernel<<<(E_st + E_ts + 255) / 256, 256, 0, stream>>>(
        ei_st, ei_st + E_st, offs_st, cur0, srt_st, E_st,
        ei_ts, ei_ts + E_ts, offs_ts, cur1, srt_ts, E_ts);

    int bpj = 512;   // 2048 blocks total (8/CU); 2-tile ILP, ~3 iters/block

    auto lin_layer = [&](const unsigned short* xs, const int* ids_s, int ns,
                         const unsigned short* xt, const int* ids_t, int nt,
                         int slot_base,
                         const float* const* pst, const float* const* pts) {
        LinJob4 LJ;
        LJ.j[0] = { xs, ids_s, Whf + (slot_base+0)*16384, pst[1], A_st, ns };
        LJ.j[1] = { xt, ids_t, Whf + (slot_base+1)*16384, pst[3], B_st, nt };
        LJ.j[2] = { xt, ids_t, Whf + (slot_base+2)*16384, pts[1], A_ts, nt };
        LJ.j[3] = { xs, ids_s, Whf + (slot_base+3)*16384, pts[3], B_ts, ns };
        lin4_kernel<<<4 * bpj, 256, 0, stream>>>(LJ, bpj);
    };
    auto gat_layer = [&](const float* const* pst, const float* const* pts,
                         const float* lnw_t, const float* lnb_t,
                         const float* lnw_s, const float* lnb_s,
                         unsigned short* out_t, unsigned short* out_s) {
        GatJob g0 = { A_st, B_st, offs_st, srt_st, pst[4], pst[5], lnw_t, lnb_t, out_t, n_tgt };
        GatJob g1 = { A_ts, B_ts, offs_ts, srt_ts, pts[4], pts[5], lnw_s, lnb_s, out_s, n_src };
        int b0 = (n_tgt + 3) / 4, b1 = (n_src + 3) / 4;
        gat2_kernel<<<b0 + b1, 256, 0, stream>>>(g0, g1, b0);
    };

    // ---- layer 1 (fused relu+LN)
    lin_layer(e_s, nid_s, n_src, e_t, nid_t, n_tgt, 0, P[0], P[1]);
    gat_layer(P[0], P[1], ln_t_w, ln_t_b, ln_s_w, ln_s_b, h_t, h_s);

    // ---- layer 2 (fp16 inputs)
    lin_layer(h_s, nullptr, n_src, h_t, nullptr, n_tgt, 4, P[2], P[3]);
    gat_layer(P[2], P[3], nullptr, nullptr, nullptr, nullptr, o_t, o_s);

    // ---- classifier
    dot_kernel<<<((size_t)EL * 8 + 255) / 256, 256, 0, stream>>>(
        o_s, o_t, eli, eli + EL, (float*)d_out, EL);
}

// Round 18
// 426.464 us; speedup vs baseline: 1.0225x; 1.0225x over previous
//
#include <hip/hip_runtime.h>

#define NEG_SLOPE 0.2f
#define LN_EPS 1e-5f
#define LOG2E 1.44269504088896f

typedef __attribute__((ext_vector_type(2))) _Float16 h16x2;
typedef __attribute__((ext_vector_type(8))) _Float16 h16x8;
typedef __attribute__((ext_vector_type(4))) float f32x4;

__device__ __forceinline__ h16x2 u2h(unsigned u) { return __builtin_bit_cast(h16x2, u); }
// f32 pair -> packed fp16 (RTZ) as raw u32 / as h16x2
__device__ __forceinline__ unsigned pk(float a, float b) {
    return __builtin_bit_cast(unsigned, __builtin_amdgcn_cvt_pkrtz(a, b));
}
__device__ __forceinline__ h16x2 pkh(float a, float b) {
    return __builtin_bit_cast(h16x2, __builtin_amdgcn_cvt_pkrtz(a, b));
}

// DPP sum over each 16-lane row: xor1(quad_perm 0xB1), xor2(0x4E),
// xor7(row_half_mirror 0x141), xor15(row_mirror 0x140) covers all 16 lanes.
#define DPP_ADD(v, ctrl) \
    v += __int_as_float(__builtin_amdgcn_update_dpp(0, __float_as_int(v), ctrl, 0xF, 0xF, true))
__device__ __forceinline__ float dpp_sum16(float v) {
    DPP_ADD(v, 0xB1);
    DPP_ADD(v, 0x4E);
    DPP_ADD(v, 0x141);
    DPP_ADD(v, 0x140);
    return v;
}
// sum over each 8-lane group: xor1, xor2, then half-row mirror (groups equal)
__device__ __forceinline__ float dpp_sum8(float v) {
    DPP_ADD(v, 0xB1);
    DPP_ADD(v, 0x4E);
    DPP_ADD(v, 0x141);
    return v;
}

// ---------- one-shot prep: 8 weight matrices + 2 embedding tables fp32->fp16,
// plus zeroing the CSR counter arrays (replaces a memset dispatch).
// blocks: [0,128) weights | [128,128+nb0) emb0 | [..+nb1) emb1 | rest: zero cnt
struct WSrc8 { const float* s[8]; };
__global__ __launch_bounds__(256) void prep_kernel(
    WSrc8 W, unsigned short* wdst,
    const float* e0, unsigned short* d0, int n0,
    const float* e1, unsigned short* d1, int nb0, int nb1,
    int* zeros, int nzero)
{
    if (blockIdx.x >= (unsigned)(128 + nb0 + nb1)) {      // zero branch: int4 stores
        int zi = (blockIdx.x - 128 - nb0 - nb1) * 1024 + threadIdx.x * 4;
        if (zi < nzero) *(int4*)(zeros + zi) = make_int4(0, 0, 0, 0);
        return;
    }
    const float* src; unsigned short* dst; int idx; int lim;
    if (blockIdx.x < 128) {
        int gidx = blockIdx.x * 256 + threadIdx.x;
        int mid = gidx >> 12;                    // 4096 threads per matrix
        src = W.s[mid]; dst = wdst + mid * 16384;
        idx = (gidx & 4095); lim = 4096;
    } else if (blockIdx.x < (unsigned)(128 + nb0)) {
        src = e0; dst = d0; idx = (blockIdx.x - 128) * 256 + threadIdx.x; lim = n0 * 16;
    } else {
        src = e1; dst = d1; idx = (blockIdx.x - 128 - nb0) * 256 + threadIdx.x; lim = 1 << 30;
    }
    if (idx >= lim) return;
    float4 v = *(const float4*)(src + idx * 4);
    uint2 o;
    o.x = pk(v.x, v.y);
    o.y = pk(v.z, v.w);
    *(uint2*)(dst + idx * 4) = o;
}

struct LinJob {
    const unsigned short* x; const int* ids; const unsigned short* Wh;
    const float* bias; unsigned short* out; int n;
};
struct LinJob4 { LinJob j[4]; };

// ---------- gather + linear via f16 MFMA, 4 jobs per launch: D[ncol][node] = W·x^T
__global__ __launch_bounds__(256) void lin4_kernel(LinJob4 P, int bpj)
{
    int jid = blockIdx.x / bpj;
    LinJob job = P.j[jid];
    int blk = blockIdx.x - jid * bpj;
    const int* __restrict__ ids = job.ids;
    const unsigned short* __restrict__ x = job.x;
    int n = job.n;

    int wv = threadIdx.x >> 6;
    int lane = threadIdx.x & 63;
    int m = lane & 15, q = lane >> 4;
    h16x8 wfrag[4][2];   // A-operand: lane holds i = wv*64+t*16+m, k = q*8 + h*32
#pragma unroll
    for (int t = 0; t < 4; ++t) {
        const unsigned short* wr = job.Wh + (wv * 64 + t * 16 + m) * 64 + q * 8;
#pragma unroll
        for (int h = 0; h < 2; ++h)
            wfrag[t][h] = *(const h16x8*)(wr + h * 32);
    }
    float4 biasv[4];
#pragma unroll
    for (int t = 0; t < 4; ++t)
        biasv[t] = *(const float4*)(job.bias + wv * 64 + t * 16 + q * 4);

    int ntiles = (n + 15) >> 4;
    for (int tile = blk; tile < ntiles; tile += bpj) {
        int row = tile * 16 + m;
        int rc = row < n ? row : n - 1;
        int src = ids ? ids[rc] : rc;
        const unsigned short* xr = x + (size_t)src * 64 + q * 8;
        h16x8 xfrag[2];
        xfrag[0] = *(const h16x8*)(xr);
        xfrag[1] = *(const h16x8*)(xr + 32);
        bool valid = row < n;
        unsigned short* orow = job.out + (size_t)row * 256 + wv * 64 + q * 4;
#pragma unroll
        for (int t = 0; t < 4; ++t) {
            f32x4 acc = {0.f, 0.f, 0.f, 0.f};
            acc = __builtin_amdgcn_mfma_f32_16x16x32_f16(wfrag[t][0], xfrag[0], acc, 0, 0, 0);
            acc = __builtin_amdgcn_mfma_f32_16x16x32_f16(wfrag[t][1], xfrag[1], acc, 0, 0, 0);
            if (valid) {
                uint2 o;
                o.x = pk(acc[0] + biasv[t].x, acc[1] + biasv[t].y);
                o.y = pk(acc[2] + biasv[t].z, acc[3] + biasv[t].w);
                *(uint2*)(orow + t * 16) = o;
            }
        }
    }
}

// ---------- CSR: histogram, both edge types in one launch
__global__ __launch_bounds__(256) void hist2_kernel(
    const int* __restrict__ ed0, int E0, int* __restrict__ cnt0,
    const int* __restrict__ ed1, int E1, int* __restrict__ cnt1)
{
    int i = blockIdx.x * 256 + threadIdx.x;
    if (i < E0) atomicAdd(&cnt0[ed0[i]], 1);
    else { int k = i - E0; if (k < E1) atomicAdd(&cnt1[ed1[k]], 1); }
}

// ---------- CSR: per-1024-chunk sums, both jobs
__global__ __launch_bounds__(256) void chunk_sum2_kernel(
    const int* __restrict__ cnt0, int* __restrict__ csum0, int n0, int nc0,
    const int* __restrict__ cnt1, int* __restrict__ csum1, int n1)
{
    const int* cnt; int* csum; int n; int blk;
    if (blockIdx.x < (unsigned)nc0) { cnt = cnt0; csum = csum0; n = n0; blk = blockIdx.x; }
    else { cnt = cnt1; csum = csum1; n = n1; blk = blockIdx.x - nc0; }
    __shared__ int wsm[4];
    int tid = threadIdx.x;
    int base = blk * 1024 + tid * 4;
    int s = 0;
#pragma unroll
    for (int k = 0; k < 4; ++k) { int i = base + k; if (i < n) s += cnt[i]; }
#pragma unroll
    for (int ofs = 32; ofs > 0; ofs >>= 1) s += __shfl_xor(s, ofs, 64);
    if ((tid & 63) == 0) wsm[tid >> 6] = s;
    __syncthreads();
    if (tid == 0) csum[blk] = wsm[0] + wsm[1] + wsm[2] + wsm[3];
}

// ---------- CSR: block-local scan + self-computed chunk offset, both jobs.
// csum holds RAW per-chunk sums; each block wave-reduces csum[0..blk) itself
// (<=64 chunks), eliminating the separate chunk-scan dispatch.
__global__ __launch_bounds__(1024) void scan_apply2_kernel(
    const int* __restrict__ cnt0, const int* __restrict__ cs0, int* __restrict__ offs0, int n0, int nc0,
    const int* __restrict__ cnt1, const int* __restrict__ cs1, int* __restrict__ offs1, int n1)
{
    const int* cnt; const int* cs; int* offs; int n; int blk;
    if (blockIdx.x < (unsigned)nc0) { cnt = cnt0; cs = cs0; offs = offs0; n = n0; blk = blockIdx.x; }
    else { cnt = cnt1; cs = cs1; offs = offs1; n = n1; blk = blockIdx.x - nc0; }
    __shared__ int wsum[16];
    __shared__ int co_s;
    int tid = threadIdx.x, lane = tid & 63, w = tid >> 6;
    if (tid < 64) {                       // chunk offset = sum of csum[0..blk)
        int v = (tid < blk) ? cs[tid] : 0;
#pragma unroll
        for (int ofs = 32; ofs > 0; ofs >>= 1) v += __shfl_xor(v, ofs, 64);
        if (tid == 0) co_s = v;
    }
    int i = blk * 1024 + tid;
    int v = (i < n) ? cnt[i] : 0;
    int incl = v;
#pragma unroll
    for (int ofs = 1; ofs < 64; ofs <<= 1) {
        int t = __shfl_up(incl, ofs, 64);
        if (lane >= ofs) incl += t;
    }
    if (lane == 63) wsum[w] = incl;
    __syncthreads();
    if (w == 0) {
        int x = (lane < 16) ? wsum[lane] : 0;
#pragma unroll
        for (int ofs = 1; ofs < 16; ofs <<= 1) {
            int t = __shfl_up(x, ofs, 64);
            if (lane >= ofs) x += t;
        }
        if (lane < 16) wsum[lane] = x;
    }
    __syncthreads();
    int woff = (w == 0) ? 0 : wsum[w - 1];
    if (i < n) offs[i + 1] = co_s + woff + incl;
    if (i == 0) offs[0] = 0;
}

// ---------- CSR: scatter into sorted order, both jobs
__global__ __launch_bounds__(256) void fill2_kernel(
    const int* __restrict__ es0, const int* __restrict__ ed0,
    const int* __restrict__ offs0, int* __restrict__ cur0, int* __restrict__ srt0, int E0,
    const int* __restrict__ es1, const int* __restrict__ ed1,
    const int* __restrict__ offs1, int* __restrict__ cur1, int* __restrict__ srt1, int E1)
{
    int i = blockIdx.x * 256 + threadIdx.x;
    if (i < E0) {
        int d = ed0[i];
        int pos = offs0[d] + atomicAdd(&cur0[d], 1);
        srt0[pos] = es0[i];
    } else {
        int k = i - E0;
        if (k < E1) {
            int d = ed1[k];
            int pos = offs1[d] + atomicAdd(&cur1[d], 1);
            srt1[pos] = es1[k];
        }
    }
}

struct GatJob {
    const unsigned short* A; const unsigned short* B;
    const int* offs; const int* srt;
    const float* att; const float* bias;
    const float* lnw; const float* lnb;
    unsigned short* out; int n_dst;
};

// ---------- fused GATv2 conv, 2 jobs per launch; fp16 tables + packed-f16 math.
// 4-way edge unroll with 4 independent states. Scalarized edge walk via
// readfirstlane; exp2 softmax with -6 shift folded. lane = h*16+g; wave per dst.
__global__ __launch_bounds__(256) void gat2_kernel(GatJob j0, GatJob j1, int blocks0)
{
    GatJob job = (blockIdx.x < (unsigned)blocks0) ? j0 : j1;
    int blk = (blockIdx.x < (unsigned)blocks0) ? blockIdx.x : blockIdx.x - blocks0;
    int d = blk * 4 + (threadIdx.x >> 6);
    int lane = threadIdx.x & 63;
    if (d >= job.n_dst) return;
    int g = lane & 15;
    const uint2* __restrict__ A2 = (const uint2*)job.A;   // 64 uint2 per node row
    float4 att4 = ((const float4*)job.att)[lane];
    h16x2 att01 = pkh(att4.x * LOG2E, att4.y * LOG2E);
    h16x2 att23 = pkh(att4.z * LOG2E, att4.w * LOG2E);
    uint2 bw = ((const uint2*)(job.B + (size_t)d * 256))[lane];
    h16x2 b01 = u2h(bw.x), b23 = u2h(bw.y);
    const h16x2 zh = {(_Float16)0.f, (_Float16)0.f};
    const h16x2 ns = {(_Float16)NEG_SLOPE, (_Float16)NEG_SLOPE};

    float den1 = 0.f, den2 = 0.f, den3 = 0.f, den4 = 0.f;
    h16x2 p01 = zh, p23 = zh, q01 = zh, q23 = zh;
    h16x2 r01 = zh, r23 = zh, s01 = zh, s23 = zh;   // four f16 accumulator states
    const int* __restrict__ srt = job.srt;
    int j0i = __builtin_amdgcn_readfirstlane(job.offs[d]);
    int j1i = __builtin_amdgcn_readfirstlane(job.offs[d + 1]);
    int j = j0i;

#define EDGE_CHAIN(WB, DEN, A01, A23) { \
        h16x2 a01 = u2h(WB.x), a23 = u2h(WB.y); \
        h16x2 t01 = a01 + b01, t23 = a23 + b23; \
        h16x2 l01 = __builtin_elementwise_max(t01 * ns, t01); \
        h16x2 l23 = __builtin_elementwise_max(t23 * ns, t23); \
        float p = __builtin_amdgcn_fdot2(l23, att23, \
                    __builtin_amdgcn_fdot2(l01, att01, -0.375f, false), false); \
        p = dpp_sum16(p);                            /* logit*log2e - 6 */ \
        float pe = __builtin_amdgcn_exp2f(p); \
        DEN += pe; \
        h16x2 peh = pkh(pe, pe); \
        A01 = a01 * peh + A01; \
        A23 = a23 * peh + A23; }

    for (; j + 3 < j1i; j += 4) {
        int s0 = __builtin_amdgcn_readfirstlane(srt[j]);
        int s1 = __builtin_amdgcn_readfirstlane(srt[j + 1]);
        int s2 = __builtin_amdgcn_readfirstlane(srt[j + 2]);
        int s3 = __builtin_amdgcn_readfirstlane(srt[j + 3]);
        uint2 w0 = A2[(size_t)s0 * 64 + lane];   // 4 gathers in flight
        uint2 w1 = A2[(size_t)s1 * 64 + lane];
        uint2 w2 = A2[(size_t)s2 * 64 + lane];
        uint2 w3 = A2[(size_t)s3 * 64 + lane];
        EDGE_CHAIN(w0, den1, p01, p23)
        EDGE_CHAIN(w1, den2, q01, q23)
        EDGE_CHAIN(w2, den3, r01, r23)
        EDGE_CHAIN(w3, den4, s01, s23)
    }
    for (; j < j1i; ++j) {
        int s0 = __builtin_amdgcn_readfirstlane(srt[j]);
        uint2 w0 = A2[(size_t)s0 * 64 + lane];
        EDGE_CHAIN(w0, den1, p01, p23)
    }
#undef EDGE_CHAIN

    float den = (den1 + den2) + (den3 + den4);
    h16x2 A01 = (p01 + q01) + (r01 + s01);
    h16x2 A23 = (p23 + q23) + (r23 + s23);
    float inv = 1.f / (den + 1e-16f);          // empty segment -> 0
    float4 acc;
    acc.x = (float)A01.x * inv;
    acc.y = (float)A01.y * inv;
    acc.z = (float)A23.x * inv;
    acc.w = (float)A23.y * inv;
    acc.x += __shfl_xor(acc.x, 16, 64);
    acc.y += __shfl_xor(acc.y, 16, 64);
    acc.z += __shfl_xor(acc.z, 16, 64);
    acc.w += __shfl_xor(acc.w, 16, 64);
    acc.x += __shfl_xor(acc.x, 32, 64);
    acc.y += __shfl_xor(acc.y, 32, 64);
    acc.z += __shfl_xor(acc.z, 32, 64);
    acc.w += __shfl_xor(acc.w, 32, 64);        // sum over heads
    float4 b4 = ((const float4*)job.bias)[g];
    float4 v;
    v.x = acc.x * 0.25f + b4.x;
    v.y = acc.y * 0.25f + b4.y;
    v.z = acc.z * 0.25f + b4.z;
    v.w = acc.w * 0.25f + b4.w;
    if (job.lnw) {                             // fused relu + LayerNorm (layer 1)
        v.x = v.x > 0.f ? v.x : 0.f;
        v.y = v.y > 0.f ? v.y : 0.f;
        v.z = v.z > 0.f ? v.z : 0.f;
        v.w = v.w > 0.f ? v.w : 0.f;
        float s  = dpp_sum16(v.x + v.y + v.z + v.w);
        float ss = dpp_sum16(v.x*v.x + v.y*v.y + v.z*v.z + v.w*v.w);
        float mu = s * (1.f / 64.f);
        float var = ss * (1.f / 64.f) - mu * mu;
        float rs = rsqrtf(var + LN_EPS);
        float4 w4 = ((const float4*)job.lnw)[g];
        float4 l4 = ((const float4*)job.lnb)[g];
        v.x = (v.x - mu) * rs * w4.x + l4.x;
        v.y = (v.y - mu) * rs * w4.y + l4.y;
        v.z = (v.z - mu) * rs * w4.z + l4.z;
        v.w = (v.w - mu) * rs * w4.w + l4.w;
    }
    if (lane < 16) {
        uint2 o;
        o.x = pk(v.x, v.y);
        o.y = pk(v.z, v.w);
        *(uint2*)(job.out + (size_t)d * 64 + g * 4) = o;
    }
}

// ---------- classifier: 8 lanes per edge, uint4 fp16 loads, fdot2 + DPP sum8
__global__ __launch_bounds__(256) void dot_kernel(
    const unsigned short* __restrict__ os, const unsigned short* __restrict__ ot,
    const int* __restrict__ ea, const int* __restrict__ eb,
    float* __restrict__ out, int n)
{
    int e = (int)((blockIdx.x * 256u + threadIdx.x) >> 3);
    int l = threadIdx.x & 7;
    if (e >= n) return;
    uint4 aw = ((const uint4*)(os + (size_t)ea[e] * 64))[l];
    uint4 bw = ((const uint4*)(ot + (size_t)eb[e] * 64))[l];
    float v = __builtin_amdgcn_fdot2(u2h(aw.x), u2h(bw.x), 0.f, false);
    v = __builtin_amdgcn_fdot2(u2h(aw.y), u2h(bw.y), v, false);
    v = __builtin_amdgcn_fdot2(u2h(aw.z), u2h(bw.z), v, false);
    v = __builtin_amdgcn_fdot2(u2h(aw.w), u2h(bw.w), v, false);
    v = dpp_sum8(v);
    if (l == 0) out[e] = v;
}

extern "C" void kernel_launch(void* const* d_in, const int* in_sizes, int n_in,
                              void* d_out, int out_size, void* d_ws, size_t ws_size,
                              hipStream_t stream)
{
    const float* src_emb = (const float*)d_in[0];
    const float* tgt_emb = (const float*)d_in[1];
    const float* P[4][6];
    for (int ci = 0; ci < 4; ++ci)
        for (int k = 0; k < 6; ++k)
            P[ci][k] = (const float*)d_in[2 + ci * 6 + k];
    const float* ln_s_w = (const float*)d_in[26];
    const float* ln_s_b = (const float*)d_in[27];
    const float* ln_t_w = (const float*)d_in[28];
    const float* ln_t_b = (const float*)d_in[29];
    const int* nid_s = (const int*)d_in[30];
    const int* nid_t = (const int*)d_in[31];
    const int* ei_st = (const int*)d_in[32];
    const int* ei_ts = (const int*)d_in[33];
    const int* eli   = (const int*)d_in[34];

    int n_src = in_sizes[30];
    int n_tgt = in_sizes[31];
    int E_st = in_sizes[32] / 2;
    int E_ts = in_sizes[33] / 2;
    int EL   = in_sizes[34] / 2;
    int nmax = n_src > n_tgt ? n_src : n_tgt;

    float* ws = (float*)d_ws;
    size_t off = 0;
    auto alloc = [&](size_t count) {     // count in floats
        float* p = ws + off;
        off += (count + 63) & ~(size_t)63;
        return p;
    };
    // 4 concurrent fp16 tables [n][256]
    unsigned short* A_st = (unsigned short*)alloc((size_t)nmax * 128);
    unsigned short* B_st = (unsigned short*)alloc((size_t)nmax * 128);
    unsigned short* A_ts = (unsigned short*)alloc((size_t)nmax * 128);
    unsigned short* B_ts = (unsigned short*)alloc((size_t)nmax * 128);
    unsigned short* Whf  = (unsigned short*)alloc(65536);   // 8 x [256x64] fp16
    // fp16 embedding copies [n][64]
    unsigned short* e_s = (unsigned short*)alloc((size_t)n_src * 32);
    unsigned short* e_t = (unsigned short*)alloc((size_t)n_tgt * 32);
    int*   offs_st = (int*)alloc((size_t)n_tgt + 1);
    int*   srt_st  = (int*)alloc((size_t)E_st);
    int*   offs_ts = (int*)alloc((size_t)n_src + 1);
    int*   srt_ts  = (int*)alloc((size_t)E_ts);
    int*   zeros   = (int*)alloc((size_t)4 * nmax + 4);   // cnt0,cnt1,cur0,cur1
    int*   csum0   = (int*)alloc(64);
    int*   csum1   = (int*)alloc(64);
    // fp16 node feature tables [n][64]
    unsigned short* h_s = (unsigned short*)alloc((size_t)n_src * 32);
    unsigned short* h_t = (unsigned short*)alloc((size_t)n_tgt * 32);
    unsigned short* o_s = (unsigned short*)alloc((size_t)n_src * 32);
    unsigned short* o_t = (unsigned short*)alloc((size_t)n_tgt * 32);
    if (off * sizeof(float) > ws_size) return;

    int* cnt0 = zeros;
    int* cnt1 = zeros + nmax;
    int* cur0 = zeros + 2 * (size_t)nmax;
    int* cur1 = zeros + 3 * (size_t)nmax;

    // ---- prep: weights + fp16 embeddings + zero CSR counters (1 launch)
    WSrc8 WS;
    for (int ci = 0; ci < 4; ++ci) { WS.s[ci*2] = P[ci][0]; WS.s[ci*2+1] = P[ci][2]; }
    int nb0 = (n_src * 16 + 255) / 256;    // float4s per table / 256
    int nb1 = (n_tgt * 16 + 255) / 256;
    int nzero = 4 * nmax;
    int nbz = (nzero + 1023) / 1024;
    prep_kernel<<<128 + nb0 + nb1 + nbz, 256, 0, stream>>>(
        WS, Whf, src_emb, e_s, n_src, tgt_emb, e_t, nb0, nb1, zeros, nzero);

    // ---- CSR build for both edge types (job0: st->dst=tgt, job1: ts->dst=src)
    int nc0 = (n_tgt + 1023) / 1024, nc1 = (n_src + 1023) / 1024;   // <= 64 each
    hist2_kernel<<<(E_st + E_ts + 255) / 256, 256, 0, stream>>>(
        ei_st + E_st, E_st, cnt0, ei_ts + E_ts, E_ts, cnt1);
    chunk_sum2_kernel<<<nc0 + nc1, 256, 0, stream>>>(cnt0, csum0, n_tgt, nc0, cnt1, csum1, n_src);
    scan_apply2_kernel<<<nc0 + nc1, 1024, 0, stream>>>(
        cnt0, csum0, offs_st, n_tgt, nc0, cnt1, csum1, offs_ts, n_src);
    fill2_kernel<<<(E_st + E_ts + 255) / 256, 256, 0, stream>>>(
        ei_st, ei_st + E_st, offs_st, cur0, srt_st, E_st,
        ei_ts, ei_ts + E_ts, offs_ts, cur1, srt_ts, E_ts);

    int bpj = 256;   // 1024 blocks total; ~12 tiles/block amortize W-frag setup

    auto lin_layer = [&](const unsigned short* xs, const int* ids_s, int ns,
                         const unsigned short* xt, const int* ids_t, int nt,
                         int slot_base,
                         const float* const* pst, const float* const* pts) {
        LinJob4 LJ;
        LJ.j[0] = { xs, ids_s, Whf + (slot_base+0)*16384, pst[1], A_st, ns };
        LJ.j[1] = { xt, ids_t, Whf + (slot_base+1)*16384, pst[3], B_st, nt };
        LJ.j[2] = { xt, ids_t, Whf + (slot_base+2)*16384, pts[1], A_ts, nt };
        LJ.j[3] = { xs, ids_s, Whf + (slot_base+3)*16384, pts[3], B_ts, ns };
        lin4_kernel<<<4 * bpj, 256, 0, stream>>>(LJ, bpj);
    };
    auto gat_layer = [&](const float* const* pst, const float* const* pts,
                         const float* lnw_t, const float* lnb_t,
                         const float* lnw_s, const float* lnb_s,
                         unsigned short* out_t, unsigned short* out_s) {
        GatJob g0 = { A_st, B_st, offs_st, srt_st, pst[4], pst[5], lnw_t, lnb_t, out_t, n_tgt };
        GatJob g1 = { A_ts, B_ts, offs_ts, srt_ts, pts[4], pts[5], lnw_s, lnb_s, out_s, n_src };
        int b0 = (n_tgt + 3) / 4, b1 = (n_src + 3) / 4;
        gat2_kernel<<<b0 + b1, 256, 0, stream>>>(g0, g1, b0);
    };

    // ---- layer 1 (fused relu+LN)
    lin_layer(e_s, nid_s, n_src, e_t, nid_t, n_tgt, 0, P[0], P[1]);
    gat_layer(P[0], P[1], ln_t_w, ln_t_b, ln_s_w, ln_s_b, h_t, h_s);

    // ---- layer 2 (fp16 inputs)
    lin_layer(h_s, nullptr, n_src, h_t, nullptr, n_tgt, 4, P[2], P[3]);
    gat_layer(P[2], P[3], nullptr, nullptr, nullptr, nullptr, o_t, o_s);

    // ---- classifier
    dot_kernel<<<((size_t)EL * 8 + 255) / 256, 256, 0, stream>>>(
        o_s, o_t, eli, eli + EL, (float*)d_out, EL);
}

// Round 19
// 421.250 us; speedup vs baseline: 1.0351x; 1.0124x over previous
//
#include <hip/hip_runtime.h>

#define NEG_SLOPE 0.2f
#define LN_EPS 1e-5f
#define LOG2E 1.44269504088896f

typedef __attribute__((ext_vector_type(2))) _Float16 h16x2;
typedef __attribute__((ext_vector_type(8))) _Float16 h16x8;
typedef __attribute__((ext_vector_type(4))) float f32x4;

__device__ __forceinline__ h16x2 u2h(unsigned u) { return __builtin_bit_cast(h16x2, u); }
// f32 pair -> packed fp16 (RTZ) as raw u32 / as h16x2
__device__ __forceinline__ unsigned pk(float a, float b) {
    return __builtin_bit_cast(unsigned, __builtin_amdgcn_cvt_pkrtz(a, b));
}
__device__ __forceinline__ h16x2 pkh(float a, float b) {
    return __builtin_bit_cast(h16x2, __builtin_amdgcn_cvt_pkrtz(a, b));
}

// DPP sum over each 16-lane row: xor1(quad_perm 0xB1), xor2(0x4E),
// xor7(row_half_mirror 0x141), xor15(row_mirror 0x140) covers all 16 lanes.
#define DPP_ADD(v, ctrl) \
    v += __int_as_float(__builtin_amdgcn_update_dpp(0, __float_as_int(v), ctrl, 0xF, 0xF, true))
__device__ __forceinline__ float dpp_sum16(float v) {
    DPP_ADD(v, 0xB1);
    DPP_ADD(v, 0x4E);
    DPP_ADD(v, 0x141);
    DPP_ADD(v, 0x140);
    return v;
}
// sum over each 8-lane group: xor1, xor2, then half-row mirror (groups equal)
__device__ __forceinline__ float dpp_sum8(float v) {
    DPP_ADD(v, 0xB1);
    DPP_ADD(v, 0x4E);
    DPP_ADD(v, 0x141);
    return v;
}

// ---------- one-shot prep: 8 weight matrices + 2 embedding tables fp32->fp16,
// plus zeroing the CSR counter arrays (replaces a memset dispatch).
// blocks: [0,128) weights | [128,128+nb0) emb0 | [..+nb1) emb1 | rest: zero cnt
struct WSrc8 { const float* s[8]; };
__global__ __launch_bounds__(256) void prep_kernel(
    WSrc8 W, unsigned short* wdst,
    const float* e0, unsigned short* d0, int n0,
    const float* e1, unsigned short* d1, int nb0, int nb1,
    int* zeros, int nzero)
{
    if (blockIdx.x >= (unsigned)(128 + nb0 + nb1)) {      // zero branch: int4 stores
        int zi = (blockIdx.x - 128 - nb0 - nb1) * 1024 + threadIdx.x * 4;
        if (zi < nzero) *(int4*)(zeros + zi) = make_int4(0, 0, 0, 0);
        return;
    }
    const float* src; unsigned short* dst; int idx; int lim;
    if (blockIdx.x < 128) {
        int gidx = blockIdx.x * 256 + threadIdx.x;
        int mid = gidx >> 12;                    // 4096 threads per matrix
        src = W.s[mid]; dst = wdst + mid * 16384;
        idx = (gidx & 4095); lim = 4096;
    } else if (blockIdx.x < (unsigned)(128 + nb0)) {
        src = e0; dst = d0; idx = (blockIdx.x - 128) * 256 + threadIdx.x; lim = n0 * 16;
    } else {
        src = e1; dst = d1; idx = (blockIdx.x - 128 - nb0) * 256 + threadIdx.x; lim = 1 << 30;
    }
    if (idx >= lim) return;
    float4 v = *(const float4*)(src + idx * 4);
    uint2 o;
    o.x = pk(v.x, v.y);
    o.y = pk(v.z, v.w);
    *(uint2*)(dst + idx * 4) = o;
}

struct LinJob {
    const unsigned short* x; const int* ids; const unsigned short* Wh;
    const float* bias; unsigned short* out; int n;
};
struct LinJob4 { LinJob j[4]; };

// ---------- gather + linear via f16 MFMA, 4 jobs per launch: D[ncol][node] = W·x^T
// x-tile staged through LDS once per block (was loaded 4x redundantly by waves).
// LDS row stride 144B -> 2-way bank aliasing on both write and b128 read (free).
__global__ __launch_bounds__(256) void lin4_kernel(LinJob4 P, int bpj)
{
    int jid = blockIdx.x / bpj;
    LinJob job = P.j[jid];
    int blk = blockIdx.x - jid * bpj;
    const int* __restrict__ ids = job.ids;
    const unsigned short* __restrict__ x = job.x;
    int n = job.n;

    __shared__ unsigned short xs[16 * 72];   // 16 rows, stride 72 ushorts (144 B)

    int tid = threadIdx.x;
    int wv = tid >> 6;
    int lane = tid & 63;
    int m = lane & 15, q = lane >> 4;
    h16x8 wfrag[4][2];   // A-operand: lane holds i = wv*64+t*16+m, k = q*8 + h*32
#pragma unroll
    for (int t = 0; t < 4; ++t) {
        const unsigned short* wr = job.Wh + (wv * 64 + t * 16 + m) * 64 + q * 8;
#pragma unroll
        for (int h = 0; h < 2; ++h)
            wfrag[t][h] = *(const h16x8*)(wr + h * 32);
    }
    float4 biasv[4];
#pragma unroll
    for (int t = 0; t < 4; ++t)
        biasv[t] = *(const float4*)(job.bias + wv * 64 + t * 16 + q * 4);

    int lr = tid >> 4, lc = tid & 15;        // cooperative loader: row lr, chunk lc
    int ntiles = (n + 15) >> 4;
    for (int tile = blk; tile < ntiles; tile += bpj) {
        int lrow = tile * 16 + lr;
        int lrc = lrow < n ? lrow : n - 1;
        int lsrc = ids ? ids[lrc] : lrc;
        // each thread loads 8 B of the 16x128B tile
        *(uint2*)(xs + lr * 72 + lc * 4) =
            *(const uint2*)(x + (size_t)lsrc * 64 + lc * 4);
        __syncthreads();
        h16x8 xfrag[2];
        xfrag[0] = *(const h16x8*)(xs + m * 72 + q * 8);
        xfrag[1] = *(const h16x8*)(xs + m * 72 + 32 + q * 8);
        __syncthreads();                      // tile consumed before next overwrite
        int row = tile * 16 + m;
        bool valid = row < n;
        unsigned short* orow = job.out + (size_t)row * 256 + wv * 64 + q * 4;
#pragma unroll
        for (int t = 0; t < 4; ++t) {
            f32x4 acc = {0.f, 0.f, 0.f, 0.f};
            acc = __builtin_amdgcn_mfma_f32_16x16x32_f16(wfrag[t][0], xfrag[0], acc, 0, 0, 0);
            acc = __builtin_amdgcn_mfma_f32_16x16x32_f16(wfrag[t][1], xfrag[1], acc, 0, 0, 0);
            if (valid) {
                uint2 o;
                o.x = pk(acc[0] + biasv[t].x, acc[1] + biasv[t].y);
                o.y = pk(acc[2] + biasv[t].z, acc[3] + biasv[t].w);
                *(uint2*)(orow + t * 16) = o;
            }
        }
    }
}

// ---------- CSR: histogram, both edge types in one launch
__global__ __launch_bounds__(256) void hist2_kernel(
    const int* __restrict__ ed0, int E0, int* __restrict__ cnt0,
    const int* __restrict__ ed1, int E1, int* __restrict__ cnt1)
{
    int i = blockIdx.x * 256 + threadIdx.x;
    if (i < E0) atomicAdd(&cnt0[ed0[i]], 1);
    else { int k = i - E0; if (k < E1) atomicAdd(&cnt1[ed1[k]], 1); }
}

// ---------- CSR: per-1024-chunk sums, both jobs
__global__ __launch_bounds__(256) void chunk_sum2_kernel(
    const int* __restrict__ cnt0, int* __restrict__ csum0, int n0, int nc0,
    const int* __restrict__ cnt1, int* __restrict__ csum1, int n1)
{
    const int* cnt; int* csum; int n; int blk;
    if (blockIdx.x < (unsigned)nc0) { cnt = cnt0; csum = csum0; n = n0; blk = blockIdx.x; }
    else { cnt = cnt1; csum = csum1; n = n1; blk = blockIdx.x - nc0; }
    __shared__ int wsm[4];
    int tid = threadIdx.x;
    int base = blk * 1024 + tid * 4;
    int s = 0;
#pragma unroll
    for (int k = 0; k < 4; ++k) { int i = base + k; if (i < n) s += cnt[i]; }
#pragma unroll
    for (int ofs = 32; ofs > 0; ofs >>= 1) s += __shfl_xor(s, ofs, 64);
    if ((tid & 63) == 0) wsm[tid >> 6] = s;
    __syncthreads();
    if (tid == 0) csum[blk] = wsm[0] + wsm[1] + wsm[2] + wsm[3];
}

// ---------- CSR: block-local scan + self-computed chunk offset, both jobs.
// csum holds RAW per-chunk sums; each block wave-reduces csum[0..blk) itself
// (<=64 chunks), eliminating the separate chunk-scan dispatch.
__global__ __launch_bounds__(1024) void scan_apply2_kernel(
    const int* __restrict__ cnt0, const int* __restrict__ cs0, int* __restrict__ offs0, int n0, int nc0,
    const int* __restrict__ cnt1, const int* __restrict__ cs1, int* __restrict__ offs1, int n1)
{
    const int* cnt; const int* cs; int* offs; int n; int blk;
    if (blockIdx.x < (unsigned)nc0) { cnt = cnt0; cs = cs0; offs = offs0; n = n0; blk = blockIdx.x; }
    else { cnt = cnt1; cs = cs1; offs = offs1; n = n1; blk = blockIdx.x - nc0; }
    __shared__ int wsum[16];
    __shared__ int co_s;
    int tid = threadIdx.x, lane = tid & 63, w = tid >> 6;
    if (tid < 64) {                       // chunk offset = sum of csum[0..blk)
        int v = (tid < blk) ? cs[tid] : 0;
#pragma unroll
        for (int ofs = 32; ofs > 0; ofs >>= 1) v += __shfl_xor(v, ofs, 64);
        if (tid == 0) co_s = v;
    }
    int i = blk * 1024 + tid;
    int v = (i < n) ? cnt[i] : 0;
    int incl = v;
#pragma unroll
    for (int ofs = 1; ofs < 64; ofs <<= 1) {
        int t = __shfl_up(incl, ofs, 64);
        if (lane >= ofs) incl += t;
    }
    if (lane == 63) wsum[w] = incl;
    __syncthreads();
    if (w == 0) {
        int x = (lane < 16) ? wsum[lane] : 0;
#pragma unroll
        for (int ofs = 1; ofs < 16; ofs <<= 1) {
            int t = __shfl_up(x, ofs, 64);
            if (lane >= ofs) x += t;
        }
        if (lane < 16) wsum[lane] = x;
    }
    __syncthreads();
    int woff = (w == 0) ? 0 : wsum[w - 1];
    if (i < n) offs[i + 1] = co_s + woff + incl;
    if (i == 0) offs[0] = 0;
}

// ---------- CSR: scatter into sorted order, both jobs
__global__ __launch_bounds__(256) void fill2_kernel(
    const int* __restrict__ es0, const int* __restrict__ ed0,
    const int* __restrict__ offs0, int* __restrict__ cur0, int* __restrict__ srt0, int E0,
    const int* __restrict__ es1, const int* __restrict__ ed1,
    const int* __restrict__ offs1, int* __restrict__ cur1, int* __restrict__ srt1, int E1)
{
    int i = blockIdx.x * 256 + threadIdx.x;
    if (i < E0) {
        int d = ed0[i];
        int pos = offs0[d] + atomicAdd(&cur0[d], 1);
        srt0[pos] = es0[i];
    } else {
        int k = i - E0;
        if (k < E1) {
            int d = ed1[k];
            int pos = offs1[d] + atomicAdd(&cur1[d], 1);
            srt1[pos] = es1[k];
        }
    }
}

struct GatJob {
    const unsigned short* A; const unsigned short* B;
    const int* offs; const int* srt;
    const float* att; const float* bias;
    const float* lnw; const float* lnb;
    unsigned short* out; int n_dst;
};

// ---------- fused GATv2 conv, 2 jobs per launch; fp16 tables + packed-f16 math.
// 4-way edge unroll with 4 independent states. Scalarized edge walk via
// readfirstlane; exp2 softmax with -6 shift folded. lane = h*16+g; wave per dst.
__global__ __launch_bounds__(256) void gat2_kernel(GatJob j0, GatJob j1, int blocks0)
{
    GatJob job = (blockIdx.x < (unsigned)blocks0) ? j0 : j1;
    int blk = (blockIdx.x < (unsigned)blocks0) ? blockIdx.x : blockIdx.x - blocks0;
    int d = blk * 4 + (threadIdx.x >> 6);
    int lane = threadIdx.x & 63;
    if (d >= job.n_dst) return;
    int g = lane & 15;
    const uint2* __restrict__ A2 = (const uint2*)job.A;   // 64 uint2 per node row
    float4 att4 = ((const float4*)job.att)[lane];
    h16x2 att01 = pkh(att4.x * LOG2E, att4.y * LOG2E);
    h16x2 att23 = pkh(att4.z * LOG2E, att4.w * LOG2E);
    uint2 bw = ((const uint2*)(job.B + (size_t)d * 256))[lane];
    h16x2 b01 = u2h(bw.x), b23 = u2h(bw.y);
    const h16x2 zh = {(_Float16)0.f, (_Float16)0.f};
    const h16x2 ns = {(_Float16)NEG_SLOPE, (_Float16)NEG_SLOPE};

    float den1 = 0.f, den2 = 0.f, den3 = 0.f, den4 = 0.f;
    h16x2 p01 = zh, p23 = zh, q01 = zh, q23 = zh;
    h16x2 r01 = zh, r23 = zh, s01 = zh, s23 = zh;   // four f16 accumulator states
    const int* __restrict__ srt = job.srt;
    int j0i = __builtin_amdgcn_readfirstlane(job.offs[d]);
    int j1i = __builtin_amdgcn_readfirstlane(job.offs[d + 1]);
    int j = j0i;

#define EDGE_CHAIN(WB, DEN, A01, A23) { \
        h16x2 a01 = u2h(WB.x), a23 = u2h(WB.y); \
        h16x2 t01 = a01 + b01, t23 = a23 + b23; \
        h16x2 l01 = __builtin_elementwise_max(t01 * ns, t01); \
        h16x2 l23 = __builtin_elementwise_max(t23 * ns, t23); \
        float p = __builtin_amdgcn_fdot2(l23, att23, \
                    __builtin_amdgcn_fdot2(l01, att01, -0.375f, false), false); \
        p = dpp_sum16(p);                            /* logit*log2e - 6 */ \
        float pe = __builtin_amdgcn_exp2f(p); \
        DEN += pe; \
        h16x2 peh = pkh(pe, pe); \
        A01 = a01 * peh + A01; \
        A23 = a23 * peh + A23; }

    for (; j + 3 < j1i; j += 4) {
        int s0 = __builtin_amdgcn_readfirstlane(srt[j]);
        int s1 = __builtin_amdgcn_readfirstlane(srt[j + 1]);
        int s2 = __builtin_amdgcn_readfirstlane(srt[j + 2]);
        int s3 = __builtin_amdgcn_readfirstlane(srt[j + 3]);
        uint2 w0 = A2[(size_t)s0 * 64 + lane];   // 4 gathers in flight
        uint2 w1 = A2[(size_t)s1 * 64 + lane];
        uint2 w2 = A2[(size_t)s2 * 64 + lane];
        uint2 w3 = A2[(size_t)s3 * 64 + lane];
        EDGE_CHAIN(w0, den1, p01, p23)
        EDGE_CHAIN(w1, den2, q01, q23)
        EDGE_CHAIN(w2, den3, r01, r23)
        EDGE_CHAIN(w3, den4, s01, s23)
    }
    for (; j < j1i; ++j) {
        int s0 = __builtin_amdgcn_readfirstlane(srt[j]);
        uint2 w0 = A2[(size_t)s0 * 64 + lane];
        EDGE_CHAIN(w0, den1, p01, p23)
    }
#undef EDGE_CHAIN

    float den = (den1 + den2) + (den3 + den4);
    h16x2 A01 = (p01 + q01) + (r01 + s01);
    h16x2 A23 = (p23 + q23) + (r23 + s23);
    float inv = 1.f / (den + 1e-16f);          // empty segment -> 0
    float4 acc;
    acc.x = (float)A01.x * inv;
    acc.y = (float)A01.y * inv;
    acc.z = (float)A23.x * inv;
    acc.w = (float)A23.y * inv;
    acc.x += __shfl_xor(acc.x, 16, 64);
    acc.y += __shfl_xor(acc.y, 16, 64);
    acc.z += __shfl_xor(acc.z, 16, 64);
    acc.w += __shfl_xor(acc.w, 16, 64);
    acc.x += __shfl_xor(acc.x, 32, 64);
    acc.y += __shfl_xor(acc.y, 32, 64);
    acc.z += __shfl_xor(acc.z, 32, 64);
    acc.w += __shfl_xor(acc.w, 32, 64);        // sum over heads
    float4 b4 = ((const float4*)job.bias)[g];
    float4 v;
    v.x = acc.x * 0.25f + b4.x;
    v.y = acc.y * 0.25f + b4.y;
    v.z = acc.z * 0.25f + b4.z;
    v.w = acc.w * 0.25f + b4.w;
    if (job.lnw) {                             // fused relu + LayerNorm (layer 1)
        v.x = v.x > 0.f ? v.x : 0.f;
        v.y = v.y > 0.f ? v.y : 0.f;
        v.z = v.z > 0.f ? v.z : 0.f;
        v.w = v.w > 0.f ? v.w : 0.f;
        float s  = dpp_sum16(v.x + v.y + v.z + v.w);
        float ss = dpp_sum16(v.x*v.x + v.y*v.y + v.z*v.z + v.w*v.w);
        float mu = s * (1.f / 64.f);
        float var = ss * (1.f / 64.f) - mu * mu;
        float rs = rsqrtf(var + LN_EPS);
        float4 w4 = ((const float4*)job.lnw)[g];
        float4 l4 = ((const float4*)job.lnb)[g];
        v.x = (v.x - mu) * rs * w4.x + l4.x;
        v.y = (v.y - mu) * rs * w4.y + l4.y;
        v.z = (v.z - mu) * rs * w4.z + l4.z;
        v.w = (v.w - mu) * rs * w4.w + l4.w;
    }
    if (lane < 16) {
        uint2 o;
        o.x = pk(v.x, v.y);
        o.y = pk(v.z, v.w);
        *(uint2*)(job.out + (size_t)d * 64 + g * 4) = o;
    }
}

// ---------- classifier: 8 lanes per edge, uint4 fp16 loads, fdot2 + DPP sum8
__global__ __launch_bounds__(256) void dot_kernel(
    const unsigned short* __restrict__ os, const unsigned short* __restrict__ ot,
    const int* __restrict__ ea, const int* __restrict__ eb,
    float* __restrict__ out, int n)
{
    int e = (int)((blockIdx.x * 256u + threadIdx.x) >> 3);
    int l = threadIdx.x & 7;
    if (e >= n) return;
    uint4 aw = ((const uint4*)(os + (size_t)ea[e] * 64))[l];
    uint4 bw = ((const uint4*)(ot + (size_t)eb[e] * 64))[l];
    float v = __builtin_amdgcn_fdot2(u2h(aw.x), u2h(bw.x), 0.f, false);
    v = __builtin_amdgcn_fdot2(u2h(aw.y), u2h(bw.y), v, false);
    v = __builtin_amdgcn_fdot2(u2h(aw.z), u2h(bw.z), v, false);
    v = __builtin_amdgcn_fdot2(u2h(aw.w), u2h(bw.w), v, false);
    v = dpp_sum8(v);
    if (l == 0) out[e] = v;
}

extern "C" void kernel_launch(void* const* d_in, const int* in_sizes, int n_in,
                              void* d_out, int out_size, void* d_ws, size_t ws_size,
                              hipStream_t stream)
{
    const float* src_emb = (const float*)d_in[0];
    const float* tgt_emb = (const float*)d_in[1];
    const float* P[4][6];
    for (int ci = 0; ci < 4; ++ci)
        for (int k = 0; k < 6; ++k)
            P[ci][k] = (const float*)d_in[2 + ci * 6 + k];
    const float* ln_s_w = (const float*)d_in[26];
    const float* ln_s_b = (const float*)d_in[27];
    const float* ln_t_w = (const float*)d_in[28];
    const float* ln_t_b = (const float*)d_in[29];
    const int* nid_s = (const int*)d_in[30];
    const int* nid_t = (const int*)d_in[31];
    const int* ei_st = (const int*)d_in[32];
    const int* ei_ts = (const int*)d_in[33];
    const int* eli   = (const int*)d_in[34];

    int n_src = in_sizes[30];
    int n_tgt = in_sizes[31];
    int E_st = in_sizes[32] / 2;
    int E_ts = in_sizes[33] / 2;
    int EL   = in_sizes[34] / 2;
    int nmax = n_src > n_tgt ? n_src : n_tgt;

    float* ws = (float*)d_ws;
    size_t off = 0;
    auto alloc = [&](size_t count) {     // count in floats
        float* p = ws + off;
        off += (count + 63) & ~(size_t)63;
        return p;
    };
    // 4 concurrent fp16 tables [n][256]
    unsigned short* A_st = (unsigned short*)alloc((size_t)nmax * 128);
    unsigned short* B_st = (unsigned short*)alloc((size_t)nmax * 128);
    unsigned short* A_ts = (unsigned short*)alloc((size_t)nmax * 128);
    unsigned short* B_ts = (unsigned short*)alloc((size_t)nmax * 128);
    unsigned short* Whf  = (unsigned short*)alloc(65536);   // 8 x [256x64] fp16
    // fp16 embedding copies [n][64]
    unsigned short* e_s = (unsigned short*)alloc((size_t)n_src * 32);
    unsigned short* e_t = (unsigned short*)alloc((size_t)n_tgt * 32);
    int*   offs_st = (int*)alloc((size_t)n_tgt + 1);
    int*   srt_st  = (int*)alloc((size_t)E_st);
    int*   offs_ts = (int*)alloc((size_t)n_src + 1);
    int*   srt_ts  = (int*)alloc((size_t)E_ts);
    int*   zeros   = (int*)alloc((size_t)4 * nmax + 4);   // cnt0,cnt1,cur0,cur1
    int*   csum0   = (int*)alloc(64);
    int*   csum1   = (int*)alloc(64);
    // fp16 node feature tables [n][64]
    unsigned short* h_s = (unsigned short*)alloc((size_t)n_src * 32);
    unsigned short* h_t = (unsigned short*)alloc((size_t)n_tgt * 32);
    unsigned short* o_s = (unsigned short*)alloc((size_t)n_src * 32);
    unsigned short* o_t = (unsigned short*)alloc((size_t)n_tgt * 32);
    if (off * sizeof(float) > ws_size) return;

    int* cnt0 = zeros;
    int* cnt1 = zeros + nmax;
    int* cur0 = zeros + 2 * (size_t)nmax;
    int* cur1 = zeros + 3 * (size_t)nmax;

    // ---- prep: weights + fp16 embeddings + zero CSR counters (1 launch)
    WSrc8 WS;
    for (int ci = 0; ci < 4; ++ci) { WS.s[ci*2] = P[ci][0]; WS.s[ci*2+1] = P[ci][2]; }
    int nb0 = (n_src * 16 + 255) / 256;    // float4s per table / 256
    int nb1 = (n_tgt * 16 + 255) / 256;
    int nzero = 4 * nmax;
    int nbz = (nzero + 1023) / 1024;
    prep_kernel<<<128 + nb0 + nb1 + nbz, 256, 0, stream>>>(
        WS, Whf, src_emb, e_s, n_src, tgt_emb, e_t, nb0, nb1, zeros, nzero);

    // ---- CSR build for both edge types (job0: st->dst=tgt, job1: ts->dst=src)
    int nc0 = (n_tgt + 1023) / 1024, nc1 = (n_src + 1023) / 1024;   // <= 64 each
    hist2_kernel<<<(E_st + E_ts + 255) / 256, 256, 0, stream>>>(
        ei_st + E_st, E_st, cnt0, ei_ts + E_ts, E_ts, cnt1);
    chunk_sum2_kernel<<<nc0 + nc1, 256, 0, stream>>>(cnt0, csum0, n_tgt, nc0, cnt1, csum1, n_src);
    scan_apply2_kernel<<<nc0 + nc1, 1024, 0, stream>>>(
        cnt0, csum0, offs_st, n_tgt, nc0, cnt1, csum1, offs_ts, n_src);
    fill2_kernel<<<(E_st + E_ts + 255) / 256, 256, 0, stream>>>(
        ei_st, ei_st + E_st, offs_st, cur0, srt_st, E_st,
        ei_ts, ei_ts + E_ts, offs_ts, cur1, srt_ts, E_ts);

    int bpj = 256;   // 1024 blocks total; ~12 tiles/block amortize W-frag setup

    auto lin_layer = [&](const unsigned short* xs, const int* ids_s, int ns,
                         const unsigned short* xt, const int* ids_t, int nt,
                         int slot_base,
                         const float* const* pst, const float* const* pts) {
        LinJob4 LJ;
        LJ.j[0] = { xs, ids_s, Whf + (slot_base+0)*16384, pst[1], A_st, ns };
        LJ.j[1] = { xt, ids_t, Whf + (slot_base+1)*16384, pst[3], B_st, nt };
        LJ.j[2] = { xt, ids_t, Whf + (slot_base+2)*16384, pts[1], A_ts, nt };
        LJ.j[3] = { xs, ids_s, Whf + (slot_base+3)*16384, pts[3], B_ts, ns };
        lin4_kernel<<<4 * bpj, 256, 0, stream>>>(LJ, bpj);
    };
    auto gat_layer = [&](const float* const* pst, const float* const* pts,
                         const float* lnw_t, const float* lnb_t,
                         const float* lnw_s, const float* lnb_s,
                         unsigned short* out_t, unsigned short* out_s) {
        GatJob g0 = { A_st, B_st, offs_st, srt_st, pst[4], pst[5], lnw_t, lnb_t, out_t, n_tgt };
        GatJob g1 = { A_ts, B_ts, offs_ts, srt_ts, pts[4], pts[5], lnw_s, lnb_s, out_s, n_src };
        int b0 = (n_tgt + 3) / 4, b1 = (n_src + 3) / 4;
        gat2_kernel<<<b0 + b1, 256, 0, stream>>>(g0, g1, b0);
    };

    // ---- layer 1 (fused relu+LN)
    lin_layer(e_s, nid_s, n_src, e_t, nid_t, n_tgt, 0, P[0], P[1]);
    gat_layer(P[0], P[1], ln_t_w, ln_t_b, ln_s_w, ln_s_b, h_t, h_s);

    // ---- layer 2 (fp16 inputs)
    lin_layer(h_s, nullptr, n_src, h_t, nullptr, n_tgt, 4, P[2], P[3]);
    gat_layer(P[2], P[3], nullptr, nullptr, nullptr, nullptr, o_t, o_s);

    // ---- classifier
    dot_kernel<<<((size_t)EL * 8 + 255) / 256, 256, 0, stream>>>(
        o_s, o_t, eli, eli + EL, (float*)d_out, EL);
}